// Round 5
// baseline (320.131 us; speedup 1.0000x reference)
//
#include <hip/hip_runtime.h>

#define N_NODES 20000
#define N_EDGES 320000
#define IN_CH 256
#define HID_CH 512

typedef unsigned short u16;
typedef __attribute__((ext_vector_type(4))) float f32x4;
typedef __attribute__((ext_vector_type(8))) short bf16x8;
typedef __attribute__((ext_vector_type(4))) u16 u16x4;

__device__ __forceinline__ float bf2f(u16 h) { return __uint_as_float((unsigned)h << 16); }
__device__ __forceinline__ u16 f2bf(float f) {  // round-to-nearest-even
    unsigned u = __float_as_uint(f);
    return (u16)((u + 0x7fffu + ((u >> 16) & 1u)) >> 16);
}

// ---------------------------------------------------------------- CSR build
__global__ void count_deg_kernel(const int* __restrict__ dst, int* __restrict__ deg, int E) {
    int i = blockIdx.x * blockDim.x + threadIdx.x;
    if (i < E) atomicAdd(&deg[dst[i]], 1);
}

__global__ void dinv_kernel(const int* __restrict__ deg, float* __restrict__ dinv, int N) {
    int i = blockIdx.x * blockDim.x + threadIdx.x;
    if (i < N) dinv[i] = rsqrtf((float)deg[i] + 1.0f);
}

__global__ __launch_bounds__(256) void scan_kernel(const int* __restrict__ deg,
                                                   int* __restrict__ row_ptr, int N) {
    __shared__ int sums[256];
    int t = threadIdx.x;
    const int CH = (N + 255) / 256;
    int base = t * CH;
    int s = 0;
    for (int i = 0; i < CH; ++i) {
        int idx = base + i;
        if (idx < N) s += deg[idx];
    }
    sums[t] = s;
    __syncthreads();
    for (int off = 1; off < 256; off <<= 1) {
        int v = (t >= off) ? sums[t - off] : 0;
        __syncthreads();
        if (t >= off) sums[t] += v;
        __syncthreads();
    }
    int run = (t == 0) ? 0 : sums[t - 1];
    for (int i = 0; i < CH; ++i) {
        int idx = base + i;
        if (idx <= N) row_ptr[idx] = run;
        if (idx < N) run += deg[idx];
    }
}

__global__ void scatter_edges_kernel(const int* __restrict__ src, const int* __restrict__ dst,
                                     const int* __restrict__ row_ptr, int* __restrict__ cursor,
                                     int* __restrict__ esrc, int E) {
    int e = blockIdx.x * blockDim.x + threadIdx.x;
    if (e >= E) return;
    int d = dst[e];
    int pos = row_ptr[d] + atomicAdd(&cursor[d], 1);
    esrc[pos] = src[e];
}

// ---------------------------------------------------------------- conversions
__global__ void f32_to_bf16_kernel(const float* __restrict__ in, u16* __restrict__ out, int n4) {
    int i = blockIdx.x * blockDim.x + threadIdx.x;
    if (i >= n4) return;
    float4 v = ((const float4*)in)[i];
    u16x4 o = {f2bf(v.x), f2bf(v.y), f2bf(v.z), f2bf(v.w)};
    ((u16x4*)out)[i] = o;
}

// W [K][N] f32 -> Wt hi/lo [N][K] bf16 — LDS-tiled 64x64 transpose + split
template <int K>
__global__ __launch_bounds__(256) void convert_w_kernel(const float* __restrict__ W,
                                                        u16* __restrict__ hi,
                                                        u16* __restrict__ lo, int N) {
    __shared__ float t[64][65];
    int k0 = blockIdx.x * 64, n0 = blockIdx.y * 64;
    int c = threadIdx.x & 63, r4 = threadIdx.x >> 6;
#pragma unroll
    for (int i = 0; i < 16; ++i) {
        int r = i * 4 + r4;
        t[r][c] = W[(size_t)(k0 + r) * N + n0 + c];
    }
    __syncthreads();
#pragma unroll
    for (int i = 0; i < 16; ++i) {
        int n = i * 4 + r4;   // output row = W column
        float f = t[c][n];    // conflict-free: stride 65
        u16 hb = f2bf(f);
        size_t o = (size_t)(n0 + n) * K + k0 + c;
        hi[o] = hb;
        lo[o] = f2bf(f - bf2f(hb));
    }
}

// ---------------------------------------------------------------- gather-aggregate
// z[n] = h[n]*dinv[n]^2 + sum_e h[src]*dinv[src]*dinv[n];  4-edge batched for MLP
template <int C>
__global__ void gather_agg_kernel(const u16* __restrict__ h, const int* __restrict__ esrc,
                                  const int* __restrict__ row_ptr, const float* __restrict__ dinv,
                                  u16* __restrict__ z_hi, u16* __restrict__ z_lo, int N) {
    constexpr int NV = C / 64;  // u16 per lane per row (4 or 8)
    typedef u16 vec_t __attribute__((ext_vector_type(NV)));
    int wave = (int)((blockIdx.x * blockDim.x + threadIdx.x) >> 6);
    int lane = threadIdx.x & 63;
    if (wave >= N) return;
    int n = wave;
    float dn = dinv[n];
    float self = dn * dn;
    const vec_t* hp = (const vec_t*)h;  // row r at vector index r*64 + lane
    float acc[NV];
    {
        vec_t v = hp[(size_t)n * 64 + lane];
#pragma unroll
        for (int j = 0; j < NV; ++j) acc[j] = bf2f(v[j]) * self;
    }
    int e0 = row_ptr[n], e1 = row_ptr[n + 1];
    int e = e0;
    for (; e + 4 <= e1; e += 4) {
        int s0 = esrc[e + 0], s1 = esrc[e + 1], s2 = esrc[e + 2], s3 = esrc[e + 3];
        float n0 = dinv[s0] * dn, n1 = dinv[s1] * dn, n2 = dinv[s2] * dn, n3 = dinv[s3] * dn;
        vec_t w0 = hp[(size_t)s0 * 64 + lane];
        vec_t w1 = hp[(size_t)s1 * 64 + lane];
        vec_t w2 = hp[(size_t)s2 * 64 + lane];
        vec_t w3 = hp[(size_t)s3 * 64 + lane];
#pragma unroll
        for (int j = 0; j < NV; ++j) {
            acc[j] = fmaf(bf2f(w0[j]), n0, acc[j]);
            acc[j] = fmaf(bf2f(w1[j]), n1, acc[j]);
            acc[j] = fmaf(bf2f(w2[j]), n2, acc[j]);
            acc[j] = fmaf(bf2f(w3[j]), n3, acc[j]);
        }
    }
    for (; e < e1; ++e) {
        int s = esrc[e];
        float nrm = dinv[s] * dn;
        vec_t w = hp[(size_t)s * 64 + lane];
#pragma unroll
        for (int j = 0; j < NV; ++j) acc[j] = fmaf(bf2f(w[j]), nrm, acc[j]);
    }
    vec_t vh, vl;
#pragma unroll
    for (int j = 0; j < NV; ++j) {
        u16 hb = f2bf(acc[j]);
        vh[j] = hb;
        vl[j] = f2bf(acc[j] - bf2f(hb));
    }
    ((vec_t*)z_hi)[(size_t)n * 64 + lane] = vh;
    ((vec_t*)z_lo)[(size_t)n * 64 + lane] = vl;
}

// ---------------------------------------------------------------- split-bf16 MFMA GEMM
// C = (Ah+Al)[M,K] @ (Bh+Bl)[K,N] + bias;  B transposed [N][K], read from GLOBAL (L2-resident).
// Only A hi/lo staged in LDS (32 KB) -> 3-4 blocks/CU. 128x128 tile, BK=64, 4 waves.
// bm from blockIdx.y (slow), bn from blockIdx.x (fast) so consecutive blocks share the A panel.
template <int K, bool RELU, bool OUT_BF16>
__global__ __launch_bounds__(256) void gemm_mfma_kernel(
        const u16* __restrict__ Ah, const u16* __restrict__ Al, const u16* __restrict__ Bh,
        const u16* __restrict__ Bl, const float* __restrict__ bias, void* __restrict__ Cout,
        int M, int N) {
    __shared__ u16 lds[2 * 128 * 64];  // planes: Ah, Al  ([128 rows][64 k], 128B rows)
    const int tid = threadIdx.x;
    const int lane = tid & 63;
    const int wid = tid >> 6;
    const int bm = blockIdx.y * 128;
    const int bn = blockIdx.x * 128;
    const int wm = (wid & 1) * 64;
    const int wn = (wid >> 1) * 64;

    f32x4 acc[4][4];
#pragma unroll
    for (int i = 0; i < 4; ++i)
#pragma unroll
        for (int j = 0; j < 4; ++j) acc[i][j] = (f32x4){0.f, 0.f, 0.f, 0.f};

    const char* ldsb = (const char*)lds;

    for (int k0 = 0; k0 < K; k0 += 64) {
        __syncthreads();  // previous compute done reading LDS
        // stage A hi/lo planes (16 KB each) via global_load_lds width16;
        // LDS dest linear, source pre-swizzled with byte ^= ((row&7)<<4)  (T2, rule #21)
#pragma unroll
        for (int p = 0; p < 2; ++p) {
            const u16* base = p ? Al : Ah;
#pragma unroll
            for (int r = 0; r < 4; ++r) {
                int chunk = r * 256 + wid * 64 + lane;  // 16B chunk id, 0..1023
                int row = chunk >> 3;                   // 8 chunks per 128B row
                int cb = (chunk & 7) << 4;
                int scb = cb ^ ((row & 7) << 4);
                int grow = min(bm + row, M - 1);
                const char* src = (const char*)(base + (size_t)grow * K + k0) + scb;
                char* dst = (char*)lds + p * 16384 + ((r * 256 + wid * 64) << 4);  // wave-uniform
                __builtin_amdgcn_global_load_lds(
                    (const __attribute__((address_space(1))) void*)src,
                    (__attribute__((address_space(3))) void*)dst, 16, 0, 0);
            }
        }
        __syncthreads();  // drains vmcnt before any wave reads

#pragma unroll
        for (int kc = 0; kc < 2; ++kc) {
            bf16x8 a_h[4], a_l[4], b_h[4], b_l[4];
            // B fragments straight from global (W panels are L2-resident)
#pragma unroll
            for (int j = 0; j < 4; ++j) {
                int rb = bn + wn + j * 16 + (lane & 15);
                size_t boff = (size_t)rb * K + (size_t)k0 + kc * 32 + ((lane >> 4) << 3);
                b_h[j] = *(const bf16x8*)(Bh + boff);
                b_l[j] = *(const bf16x8*)(Bl + boff);
            }
            int cb = (kc << 6) + ((lane >> 4) << 4);
#pragma unroll
            for (int i = 0; i < 4; ++i) {
                int ra = wm + i * 16 + (lane & 15);
                int off_a = ra * 128 + (cb ^ ((ra & 7) << 4));
                a_h[i] = *(const bf16x8*)(ldsb + off_a);
                a_l[i] = *(const bf16x8*)(ldsb + 16384 + off_a);
            }
#pragma unroll
            for (int i = 0; i < 4; ++i)
#pragma unroll
                for (int j = 0; j < 4; ++j) {
                    acc[i][j] = __builtin_amdgcn_mfma_f32_16x16x32_bf16(a_h[i], b_h[j], acc[i][j], 0, 0, 0);
                    acc[i][j] = __builtin_amdgcn_mfma_f32_16x16x32_bf16(a_l[i], b_h[j], acc[i][j], 0, 0, 0);
                    acc[i][j] = __builtin_amdgcn_mfma_f32_16x16x32_bf16(a_h[i], b_l[j], acc[i][j], 0, 0, 0);
                }
        }
    }

    // epilogue: C/D layout col=lane&15, row=(lane>>4)*4+t  (m89/m91 verified)
#pragma unroll
    for (int j = 0; j < 4; ++j) {
        int gc = bn + wn + j * 16 + (lane & 15);
        float bv = bias[gc];
#pragma unroll
        for (int i = 0; i < 4; ++i) {
#pragma unroll
            for (int t = 0; t < 4; ++t) {
                int gr = bm + wm + i * 16 + ((lane >> 4) << 2) + t;
                if (gr < M) {
                    float v = acc[i][j][t] + bv;
                    if (RELU) v = fmaxf(v, 0.f);
                    if (OUT_BF16)
                        ((u16*)Cout)[(size_t)gr * N + gc] = f2bf(v);
                    else
                        ((float*)Cout)[(size_t)gr * N + gc] = v;
                }
            }
        }
    }
}

// ---------------------------------------------------------------- launch
extern "C" void kernel_launch(void* const* d_in, const int* in_sizes, int n_in,
                              void* d_out, int out_size, void* d_ws, size_t ws_size,
                              hipStream_t stream) {
    const float* x  = (const float*)d_in[0];
    const int*   ei = (const int*)d_in[1];
    const float* W1 = (const float*)d_in[2];
    const float* b1 = (const float*)d_in[3];
    const float* W2 = (const float*)d_in[4];
    const float* b2 = (const float*)d_in[5];
    const int* src = ei;
    const int* dst = ei + N_EDGES;

    char* ws = (char*)d_ws;
    size_t off = 0;
    auto alloc = [&](size_t bytes) {
        void* p = ws + off;
        off = (off + bytes + 255) & ~(size_t)255;
        return p;
    };
    int*   deg     = (int*)alloc(N_NODES * 4);
    int*   row_ptr = (int*)alloc((N_NODES + 1) * 4);
    float* dinv    = (float*)alloc(N_NODES * 4);
    int*   esrc    = (int*)alloc(N_EDGES * 4);
    u16*   wt1_hi  = (u16*)alloc((size_t)IN_CH * HID_CH * 2);
    u16*   wt1_lo  = (u16*)alloc((size_t)IN_CH * HID_CH * 2);
    u16*   wt2_hi  = (u16*)alloc((size_t)HID_CH * HID_CH * 2);
    u16*   wt2_lo  = (u16*)alloc((size_t)HID_CH * HID_CH * 2);
    // overlay region: {xb, z1_hi, z1_lo} then {z2_hi, z2_lo}
    char*  R       = (char*)alloc((size_t)N_NODES * HID_CH * 2 * 2);  // 40.96 MB
    u16* xb    = (u16*)R;                                       // [N, 256]
    u16* z1_hi = (u16*)(R + (size_t)N_NODES * IN_CH * 2);       // [N, 256]
    u16* z1_lo = (u16*)(R + (size_t)N_NODES * IN_CH * 4);       // [N, 256]
    u16* z2_hi = (u16*)R;                                       // [N, 512] (over dead xb+z1_hi)
    u16* z2_lo = (u16*)(R + (size_t)N_NODES * HID_CH * 2);      // [N, 512] (over dead z1_lo)
    u16* h1    = (u16*)d_out;  // bf16 h1 scratch in d_out (dead before final GEMM writes)

    // CSR + dinv
    hipMemsetAsync(deg, 0, N_NODES * 4, stream);
    count_deg_kernel<<<(N_EDGES + 255) / 256, 256, 0, stream>>>(dst, deg, N_EDGES);
    dinv_kernel<<<(N_NODES + 255) / 256, 256, 0, stream>>>(deg, dinv, N_NODES);
    scan_kernel<<<1, 256, 0, stream>>>(deg, row_ptr, N_NODES);
    hipMemsetAsync(deg, 0, N_NODES * 4, stream);
    scatter_edges_kernel<<<(N_EDGES + 255) / 256, 256, 0, stream>>>(src, dst, row_ptr, deg, esrc,
                                                                    N_EDGES);

    // conversions
    f32_to_bf16_kernel<<<(N_NODES * IN_CH / 4 + 255) / 256, 256, 0, stream>>>(
        x, xb, N_NODES * IN_CH / 4);
    {
        dim3 g1(IN_CH / 64, HID_CH / 64);
        convert_w_kernel<IN_CH><<<g1, 256, 0, stream>>>(W1, wt1_hi, wt1_lo, HID_CH);
        dim3 g2(HID_CH / 64, HID_CH / 64);
        convert_w_kernel<HID_CH><<<g2, 256, 0, stream>>>(W2, wt2_hi, wt2_lo, HID_CH);
    }

    // layer 1: z1 = P @ xb ; h1 = relu(z1 @ W1 + b1)  (bf16 out)
    gather_agg_kernel<IN_CH><<<(N_NODES + 3) / 4, 256, 0, stream>>>(xb, esrc, row_ptr, dinv, z1_hi,
                                                                    z1_lo, N_NODES);
    {
        dim3 grid(HID_CH / 128, (N_NODES + 127) / 128);
        gemm_mfma_kernel<IN_CH, true, true><<<grid, 256, 0, stream>>>(
            z1_hi, z1_lo, wt1_hi, wt1_lo, b1, h1, N_NODES, HID_CH);
    }

    // layer 2: z2 = P @ h1 ; out = z2 @ W2 + b2  (fp32 out)
    gather_agg_kernel<HID_CH><<<(N_NODES + 3) / 4, 256, 0, stream>>>(h1, esrc, row_ptr, dinv,
                                                                     z2_hi, z2_lo, N_NODES);
    {
        dim3 grid(HID_CH / 128, (N_NODES + 127) / 128);
        gemm_mfma_kernel<HID_CH, false, false><<<grid, 256, 0, stream>>>(
            z2_hi, z2_lo, wt2_hi, wt2_lo, b2, (float*)d_out, N_NODES, HID_CH);
    }
}

// Round 6
// 253.131 us; speedup vs baseline: 1.2647x; 1.2647x over previous
//
#include <hip/hip_runtime.h>

#define N_NODES 20000
#define N_EDGES 320000
#define IN_CH 256
#define HID_CH 512

typedef unsigned short u16;
typedef __attribute__((ext_vector_type(4))) float f32x4;
typedef __attribute__((ext_vector_type(8))) short bf16x8;
typedef __attribute__((ext_vector_type(4))) u16 u16x4;

__device__ __forceinline__ float bf2f(u16 h) { return __uint_as_float((unsigned)h << 16); }
__device__ __forceinline__ u16 f2bf(float f) {  // round-to-nearest-even
    unsigned u = __float_as_uint(f);
    return (u16)((u + 0x7fffu + ((u >> 16) & 1u)) >> 16);
}

// ---------------------------------------------------------------- CSR build
__global__ void count_deg_kernel(const int* __restrict__ dst, int* __restrict__ deg, int E) {
    int i = blockIdx.x * blockDim.x + threadIdx.x;
    if (i < E) atomicAdd(&deg[dst[i]], 1);
}

__global__ void dinv_kernel(const int* __restrict__ deg, float* __restrict__ dinv, int N) {
    int i = blockIdx.x * blockDim.x + threadIdx.x;
    if (i < N) dinv[i] = rsqrtf((float)deg[i] + 1.0f);
}

__global__ __launch_bounds__(256) void scan_kernel(const int* __restrict__ deg,
                                                   int* __restrict__ row_ptr, int N) {
    __shared__ int sums[256];
    int t = threadIdx.x;
    const int CH = (N + 255) / 256;
    int base = t * CH;
    int s = 0;
    for (int i = 0; i < CH; ++i) {
        int idx = base + i;
        if (idx < N) s += deg[idx];
    }
    sums[t] = s;
    __syncthreads();
    for (int off = 1; off < 256; off <<= 1) {
        int v = (t >= off) ? sums[t - off] : 0;
        __syncthreads();
        if (t >= off) sums[t] += v;
        __syncthreads();
    }
    int run = (t == 0) ? 0 : sums[t - 1];
    for (int i = 0; i < CH; ++i) {
        int idx = base + i;
        if (idx <= N) row_ptr[idx] = run;
        if (idx < N) run += deg[idx];
    }
}

__global__ void scatter_edges_kernel(const int* __restrict__ src, const int* __restrict__ dst,
                                     const int* __restrict__ row_ptr, int* __restrict__ cursor,
                                     int* __restrict__ esrc, int E) {
    int e = blockIdx.x * blockDim.x + threadIdx.x;
    if (e >= E) return;
    int d = dst[e];
    int pos = row_ptr[d] + atomicAdd(&cursor[d], 1);
    esrc[pos] = src[e];
}

// ---------------------------------------------------------------- conversions
__global__ void f32_to_bf16_kernel(const float* __restrict__ in, u16* __restrict__ out, int n4) {
    int i = blockIdx.x * blockDim.x + threadIdx.x;
    if (i >= n4) return;
    float4 v = ((const float4*)in)[i];
    u16x4 o = {f2bf(v.x), f2bf(v.y), f2bf(v.z), f2bf(v.w)};
    ((u16x4*)out)[i] = o;
}

// W [K][N] f32 -> Wt hi/lo [N][K] bf16 — LDS-tiled 64x64 transpose + split
template <int K>
__global__ __launch_bounds__(256) void convert_w_kernel(const float* __restrict__ W,
                                                        u16* __restrict__ hi,
                                                        u16* __restrict__ lo, int N) {
    __shared__ float t[64][65];
    int k0 = blockIdx.x * 64, n0 = blockIdx.y * 64;
    int c = threadIdx.x & 63, r4 = threadIdx.x >> 6;
#pragma unroll
    for (int i = 0; i < 16; ++i) {
        int r = i * 4 + r4;
        t[r][c] = W[(size_t)(k0 + r) * N + n0 + c];
    }
    __syncthreads();
#pragma unroll
    for (int i = 0; i < 16; ++i) {
        int n = i * 4 + r4;   // output row = W column
        float f = t[c][n];    // conflict-free: stride 65
        u16 hb = f2bf(f);
        size_t o = (size_t)(n0 + n) * K + k0 + c;
        hi[o] = hb;
        lo[o] = f2bf(f - bf2f(hb));
    }
}

// ---------------------------------------------------------------- gather-aggregate
// z[n] = h[n]*dinv[n]^2 + sum_e h[src]*dinv[src]*dinv[n];  8-edge batched for MLP
template <int C>
__global__ void gather_agg_kernel(const u16* __restrict__ h, const int* __restrict__ esrc,
                                  const int* __restrict__ row_ptr, const float* __restrict__ dinv,
                                  u16* __restrict__ z_hi, u16* __restrict__ z_lo, int N) {
    constexpr int NV = C / 64;  // u16 per lane per row (4 or 8)
    typedef u16 vec_t __attribute__((ext_vector_type(NV)));
    int wave = (int)((blockIdx.x * blockDim.x + threadIdx.x) >> 6);
    int lane = threadIdx.x & 63;
    if (wave >= N) return;
    int n = wave;
    float dn = dinv[n];
    float self = dn * dn;
    const vec_t* hp = (const vec_t*)h;  // row r at vector index r*64 + lane
    float acc[NV];
    {
        vec_t v = hp[(size_t)n * 64 + lane];
#pragma unroll
        for (int j = 0; j < NV; ++j) acc[j] = bf2f(v[j]) * self;
    }
    int e0 = row_ptr[n], e1 = row_ptr[n + 1];
    int e = e0;
    for (; e + 8 <= e1; e += 8) {
        int s[8];
        float nr[8];
        vec_t w[8];
#pragma unroll
        for (int b = 0; b < 8; ++b) s[b] = esrc[e + b];
#pragma unroll
        for (int b = 0; b < 8; ++b) nr[b] = dinv[s[b]] * dn;
#pragma unroll
        for (int b = 0; b < 8; ++b) w[b] = hp[(size_t)s[b] * 64 + lane];
#pragma unroll
        for (int b = 0; b < 8; ++b)
#pragma unroll
            for (int j = 0; j < NV; ++j) acc[j] = fmaf(bf2f(w[b][j]), nr[b], acc[j]);
    }
    for (; e < e1; ++e) {
        int s = esrc[e];
        float nrm = dinv[s] * dn;
        vec_t w = hp[(size_t)s * 64 + lane];
#pragma unroll
        for (int j = 0; j < NV; ++j) acc[j] = fmaf(bf2f(w[j]), nrm, acc[j]);
    }
    vec_t vh, vl;
#pragma unroll
    for (int j = 0; j < NV; ++j) {
        u16 hb = f2bf(acc[j]);
        vh[j] = hb;
        vl[j] = f2bf(acc[j] - bf2f(hb));
    }
    ((vec_t*)z_hi)[(size_t)n * 64 + lane] = vh;
    ((vec_t*)z_lo)[(size_t)n * 64 + lane] = vl;
}

// ---------------------------------------------------------------- split-bf16 MFMA GEMM
// C = (Ah+Al)[M,K] @ (Bh+Bl)[K,N] + bias;  B transposed [N][K].
// BM=128, BN=128, BK=32; 8 waves (wave tile 64x32); double-buffered LDS (2 x 32KB);
// 2-phase pipeline: STAGE(next) issued before compute(cur), one barrier/iter.
// 1-D grid with bijective XCD-chunked swizzle (m204) so same-A blocks share an XCD L2.
template <int K, bool RELU, bool OUT_BF16>
__global__ __launch_bounds__(512, 4) void gemm_mfma_kernel(
        const u16* __restrict__ Ah, const u16* __restrict__ Al, const u16* __restrict__ Bh,
        const u16* __restrict__ Bl, const float* __restrict__ bias, void* __restrict__ Cout,
        int M, int N) {
    // planes per buffer: 0=Ah 1=Al 2=Bh 3=Bl, each [128 rows][32 k] = 8 KB, rows 64 B
    __shared__ u16 lds[2][4][128 * 32];
    const int tid = threadIdx.x;
    const int lane = tid & 63;
    const int wid = tid >> 6;

    // bijective XCD-chunked swizzle
    const int nmt = (M + 127) / 128;
    const int total = nmt * 4;
    int bid = blockIdx.x;
    int q = total >> 3, r = total & 7;
    int xcd = bid & 7, p = bid >> 3;
    int lin = (xcd < r) ? (xcd * (q + 1) + p) : (r * (q + 1) + (xcd - r) * q + p);
    const int bm = (lin >> 2) * 128;
    const int bn = (lin & 3) * 128;

    const int wm = (wid & 1) * 64;   // 2 wave-rows
    const int wn = (wid >> 1) * 32;  // 4 wave-cols

    f32x4 acc[4][2];
#pragma unroll
    for (int i = 0; i < 4; ++i)
#pragma unroll
        for (int j = 0; j < 2; ++j) acc[i][j] = (f32x4){0.f, 0.f, 0.f, 0.f};

    // staging geometry: 512 chunks of 16B per plane; chunk = tid
    const int srow = tid >> 2;              // 0..127
    const int scb = ((tid & 3) << 4);       // 0,16,32,48
    const int sscb = scb ^ ((srow & 3) << 4);  // pre-swizzled source byte col
    const int grA = min(bm + srow, M - 1);
    const int grB = bn + srow;
    const char* srcAh = (const char*)(Ah + (size_t)grA * K) + sscb;
    const char* srcAl = (const char*)(Al + (size_t)grA * K) + sscb;
    const char* srcBh = (const char*)(Bh + (size_t)grB * K) + sscb;
    const char* srcBl = (const char*)(Bl + (size_t)grB * K) + sscb;
    const int dstoff = (wid * 64) << 4;  // wave-uniform LDS byte offset within plane

#define STAGE(buf, k0)                                                                   \
    do {                                                                                 \
        size_t kb = (size_t)(k0) * 2;                                                    \
        __builtin_amdgcn_global_load_lds(                                                \
            (const __attribute__((address_space(1))) void*)(srcAh + kb),                 \
            (__attribute__((address_space(3))) void*)((char*)&lds[buf][0][0] + dstoff),  \
            16, 0, 0);                                                                   \
        __builtin_amdgcn_global_load_lds(                                                \
            (const __attribute__((address_space(1))) void*)(srcAl + kb),                 \
            (__attribute__((address_space(3))) void*)((char*)&lds[buf][1][0] + dstoff),  \
            16, 0, 0);                                                                   \
        __builtin_amdgcn_global_load_lds(                                                \
            (const __attribute__((address_space(1))) void*)(srcBh + kb),                 \
            (__attribute__((address_space(3))) void*)((char*)&lds[buf][2][0] + dstoff),  \
            16, 0, 0);                                                                   \
        __builtin_amdgcn_global_load_lds(                                                \
            (const __attribute__((address_space(1))) void*)(srcBl + kb),                 \
            (__attribute__((address_space(3))) void*)((char*)&lds[buf][3][0] + dstoff),  \
            16, 0, 0);                                                                   \
    } while (0)

    STAGE(0, 0);
    __syncthreads();

    const int NT = K / 32;
    const int kb = (lane >> 4) << 4;  // fragment k byte-offset within 64B row
#pragma unroll 2
    for (int t = 0; t < NT; ++t) {
        int cur = t & 1;
        if (t + 1 < NT) STAGE(cur ^ 1, (t + 1) * 32);

        const char* L = (const char*)&lds[cur][0][0];
        bf16x8 a_h[4], a_l[4], b_h[2], b_l[2];
#pragma unroll
        for (int i = 0; i < 4; ++i) {
            int ra = wm + i * 16 + (lane & 15);
            int off = ra * 64 + (kb ^ ((ra & 3) << 4));
            a_h[i] = *(const bf16x8*)(L + off);
            a_l[i] = *(const bf16x8*)(L + 8192 + off);
        }
#pragma unroll
        for (int j = 0; j < 2; ++j) {
            int rb = wn + j * 16 + (lane & 15);
            int off = rb * 64 + (kb ^ ((rb & 3) << 4));
            b_h[j] = *(const bf16x8*)(L + 16384 + off);
            b_l[j] = *(const bf16x8*)(L + 24576 + off);
        }
#pragma unroll
        for (int i = 0; i < 4; ++i)
#pragma unroll
            for (int j = 0; j < 2; ++j) {
                acc[i][j] = __builtin_amdgcn_mfma_f32_16x16x32_bf16(a_h[i], b_h[j], acc[i][j], 0, 0, 0);
                acc[i][j] = __builtin_amdgcn_mfma_f32_16x16x32_bf16(a_l[i], b_h[j], acc[i][j], 0, 0, 0);
                acc[i][j] = __builtin_amdgcn_mfma_f32_16x16x32_bf16(a_h[i], b_l[j], acc[i][j], 0, 0, 0);
            }
        __syncthreads();  // drains vmcnt: next buffer staged; cur buffer free for overwrite
    }
#undef STAGE

    // epilogue: C/D layout col=lane&15, row=(lane>>4)*4+t  (m89/m91 verified)
#pragma unroll
    for (int j = 0; j < 2; ++j) {
        int gc = bn + wn + j * 16 + (lane & 15);
        float bv = bias[gc];
#pragma unroll
        for (int i = 0; i < 4; ++i) {
#pragma unroll
            for (int t = 0; t < 4; ++t) {
                int gr = bm + wm + i * 16 + ((lane >> 4) << 2) + t;
                if (gr < M) {
                    float v = acc[i][j][t] + bv;
                    if (RELU) v = fmaxf(v, 0.f);
                    if (OUT_BF16)
                        ((u16*)Cout)[(size_t)gr * N + gc] = f2bf(v);
                    else
                        ((float*)Cout)[(size_t)gr * N + gc] = v;
                }
            }
        }
    }
}

// ---------------------------------------------------------------- launch
extern "C" void kernel_launch(void* const* d_in, const int* in_sizes, int n_in,
                              void* d_out, int out_size, void* d_ws, size_t ws_size,
                              hipStream_t stream) {
    const float* x  = (const float*)d_in[0];
    const int*   ei = (const int*)d_in[1];
    const float* W1 = (const float*)d_in[2];
    const float* b1 = (const float*)d_in[3];
    const float* W2 = (const float*)d_in[4];
    const float* b2 = (const float*)d_in[5];
    const int* src = ei;
    const int* dst = ei + N_EDGES;

    char* ws = (char*)d_ws;
    size_t off = 0;
    auto alloc = [&](size_t bytes) {
        void* p = ws + off;
        off = (off + bytes + 255) & ~(size_t)255;
        return p;
    };
    int*   deg     = (int*)alloc(N_NODES * 4);
    int*   row_ptr = (int*)alloc((N_NODES + 1) * 4);
    float* dinv    = (float*)alloc(N_NODES * 4);
    int*   esrc    = (int*)alloc(N_EDGES * 4);
    u16*   wt1_hi  = (u16*)alloc((size_t)IN_CH * HID_CH * 2);
    u16*   wt1_lo  = (u16*)alloc((size_t)IN_CH * HID_CH * 2);
    u16*   wt2_hi  = (u16*)alloc((size_t)HID_CH * HID_CH * 2);
    u16*   wt2_lo  = (u16*)alloc((size_t)HID_CH * HID_CH * 2);
    // overlay region: {xb, z1_hi, z1_lo} then {z2_hi, z2_lo}
    char*  R       = (char*)alloc((size_t)N_NODES * HID_CH * 2 * 2);  // 40.96 MB
    u16* xb    = (u16*)R;                                       // [N, 256]
    u16* z1_hi = (u16*)(R + (size_t)N_NODES * IN_CH * 2);       // [N, 256]
    u16* z1_lo = (u16*)(R + (size_t)N_NODES * IN_CH * 4);       // [N, 256]
    u16* z2_hi = (u16*)R;                                       // [N, 512] (over dead xb+z1_hi)
    u16* z2_lo = (u16*)(R + (size_t)N_NODES * HID_CH * 2);      // [N, 512] (over dead z1_lo)
    u16* h1    = (u16*)d_out;  // bf16 h1 scratch in d_out (dead before final GEMM writes)

    // CSR + dinv
    hipMemsetAsync(deg, 0, N_NODES * 4, stream);
    count_deg_kernel<<<(N_EDGES + 255) / 256, 256, 0, stream>>>(dst, deg, N_EDGES);
    dinv_kernel<<<(N_NODES + 255) / 256, 256, 0, stream>>>(deg, dinv, N_NODES);
    scan_kernel<<<1, 256, 0, stream>>>(deg, row_ptr, N_NODES);
    hipMemsetAsync(deg, 0, N_NODES * 4, stream);
    scatter_edges_kernel<<<(N_EDGES + 255) / 256, 256, 0, stream>>>(src, dst, row_ptr, deg, esrc,
                                                                    N_EDGES);

    // conversions
    f32_to_bf16_kernel<<<(N_NODES * IN_CH / 4 + 255) / 256, 256, 0, stream>>>(
        x, xb, N_NODES * IN_CH / 4);
    {
        dim3 g1(IN_CH / 64, HID_CH / 64);
        convert_w_kernel<IN_CH><<<g1, 256, 0, stream>>>(W1, wt1_hi, wt1_lo, HID_CH);
        dim3 g2(HID_CH / 64, HID_CH / 64);
        convert_w_kernel<HID_CH><<<g2, 256, 0, stream>>>(W2, wt2_hi, wt2_lo, HID_CH);
    }

    const int NMT = (N_NODES + 127) / 128;  // 157
    // layer 1: z1 = P @ xb ; h1 = relu(z1 @ W1 + b1)  (bf16 out)
    gather_agg_kernel<IN_CH><<<(N_NODES + 3) / 4, 256, 0, stream>>>(xb, esrc, row_ptr, dinv, z1_hi,
                                                                    z1_lo, N_NODES);
    gemm_mfma_kernel<IN_CH, true, true><<<NMT * 4, 512, 0, stream>>>(
        z1_hi, z1_lo, wt1_hi, wt1_lo, b1, h1, N_NODES, HID_CH);

    // layer 2: z2 = P @ h1 ; out = z2 @ W2 + b2  (fp32 out)
    gather_agg_kernel<HID_CH><<<(N_NODES + 3) / 4, 256, 0, stream>>>(h1, esrc, row_ptr, dinv,
                                                                     z2_hi, z2_lo, N_NODES);
    gemm_mfma_kernel<HID_CH, false, false><<<NMT * 4, 512, 0, stream>>>(
        z2_hi, z2_lo, wt2_hi, wt2_lo, b2, (float*)d_out, N_NODES, HID_CH);
}

// Round 7
// 247.208 us; speedup vs baseline: 1.2950x; 1.0240x over previous
//
#include <hip/hip_runtime.h>

#define N_NODES 20000
#define N_EDGES 320000
#define IN_CH 256
#define HID_CH 512

typedef unsigned short u16;
typedef __attribute__((ext_vector_type(4))) float f32x4;
typedef __attribute__((ext_vector_type(8))) short bf16x8;
typedef __attribute__((ext_vector_type(4))) u16 u16x4;

__device__ __forceinline__ float bf2f(u16 h) { return __uint_as_float((unsigned)h << 16); }
__device__ __forceinline__ u16 f2bf(float f) {  // round-to-nearest-even
    unsigned u = __float_as_uint(f);
    return (u16)((u + 0x7fffu + ((u >> 16) & 1u)) >> 16);
}

// ---------------------------------------------------------------- CSR build
__global__ void count_deg_kernel(const int* __restrict__ dst, int* __restrict__ deg, int E) {
    int i = blockIdx.x * blockDim.x + threadIdx.x;
    if (i < E) atomicAdd(&deg[dst[i]], 1);
}

__global__ void dinv_kernel(const int* __restrict__ deg, float* __restrict__ dinv, int N) {
    int i = blockIdx.x * blockDim.x + threadIdx.x;
    if (i < N) dinv[i] = rsqrtf((float)deg[i] + 1.0f);
}

__global__ __launch_bounds__(256) void scan_kernel(const int* __restrict__ deg,
                                                   int* __restrict__ row_ptr, int N) {
    __shared__ int sums[256];
    int t = threadIdx.x;
    const int CH = (N + 255) / 256;
    int base = t * CH;
    int s = 0;
    for (int i = 0; i < CH; ++i) {
        int idx = base + i;
        if (idx < N) s += deg[idx];
    }
    sums[t] = s;
    __syncthreads();
    for (int off = 1; off < 256; off <<= 1) {
        int v = (t >= off) ? sums[t - off] : 0;
        __syncthreads();
        if (t >= off) sums[t] += v;
        __syncthreads();
    }
    int run = (t == 0) ? 0 : sums[t - 1];
    for (int i = 0; i < CH; ++i) {
        int idx = base + i;
        if (idx <= N) row_ptr[idx] = run;
        if (idx < N) run += deg[idx];
    }
}

__global__ void scatter_edges_kernel(const int* __restrict__ src, const int* __restrict__ dst,
                                     const int* __restrict__ row_ptr, int* __restrict__ cursor,
                                     int* __restrict__ esrc, int E) {
    int e = blockIdx.x * blockDim.x + threadIdx.x;
    if (e >= E) return;
    int d = dst[e];
    int pos = row_ptr[d] + atomicAdd(&cursor[d], 1);
    esrc[pos] = src[e];
}

// ---------------------------------------------------------------- conversions
__global__ void f32_to_bf16_kernel(const float* __restrict__ in, u16* __restrict__ out, int n4) {
    int i = blockIdx.x * blockDim.x + threadIdx.x;
    if (i >= n4) return;
    float4 v = ((const float4*)in)[i];
    u16x4 o = {f2bf(v.x), f2bf(v.y), f2bf(v.z), f2bf(v.w)};
    ((u16x4*)out)[i] = o;
}

// W [K][N] f32 -> Wt hi/lo [N][K] bf16 — LDS-tiled 64x64 transpose + split
template <int K>
__global__ __launch_bounds__(256) void convert_w_kernel(const float* __restrict__ W,
                                                        u16* __restrict__ hi,
                                                        u16* __restrict__ lo, int N) {
    __shared__ float t[64][65];
    int k0 = blockIdx.x * 64, n0 = blockIdx.y * 64;
    int c = threadIdx.x & 63, r4 = threadIdx.x >> 6;
#pragma unroll
    for (int i = 0; i < 16; ++i) {
        int r = i * 4 + r4;
        t[r][c] = W[(size_t)(k0 + r) * N + n0 + c];
    }
    __syncthreads();
#pragma unroll
    for (int i = 0; i < 16; ++i) {
        int n = i * 4 + r4;   // output row = W column
        float f = t[c][n];    // conflict-free: stride 65
        u16 hb = f2bf(f);
        size_t o = (size_t)(n0 + n) * K + k0 + c;
        hi[o] = hb;
        lo[o] = f2bf(f - bf2f(hb));
    }
}

// ---------------------------------------------------------------- gather-aggregate
// z[n] = h[n]*dinv[n]^2 + sum_e h[src]*dinv[src]*dinv[n];  8-edge batched for MLP
template <int C>
__global__ void gather_agg_kernel(const u16* __restrict__ h, const int* __restrict__ esrc,
                                  const int* __restrict__ row_ptr, const float* __restrict__ dinv,
                                  u16* __restrict__ z_hi, u16* __restrict__ z_lo, int N) {
    constexpr int NV = C / 64;  // u16 per lane per row (4 or 8)
    typedef u16 vec_t __attribute__((ext_vector_type(NV)));
    int wave = (int)((blockIdx.x * blockDim.x + threadIdx.x) >> 6);
    int lane = threadIdx.x & 63;
    if (wave >= N) return;
    int n = wave;
    float dn = dinv[n];
    float self = dn * dn;
    const vec_t* hp = (const vec_t*)h;  // row r at vector index r*64 + lane
    float acc[NV];
    {
        vec_t v = hp[(size_t)n * 64 + lane];
#pragma unroll
        for (int j = 0; j < NV; ++j) acc[j] = bf2f(v[j]) * self;
    }
    int e0 = row_ptr[n], e1 = row_ptr[n + 1];
    int e = e0;
    for (; e + 8 <= e1; e += 8) {
        int s[8];
        float nr[8];
        vec_t w[8];
#pragma unroll
        for (int b = 0; b < 8; ++b) s[b] = esrc[e + b];
#pragma unroll
        for (int b = 0; b < 8; ++b) nr[b] = dinv[s[b]] * dn;
#pragma unroll
        for (int b = 0; b < 8; ++b) w[b] = hp[(size_t)s[b] * 64 + lane];
#pragma unroll
        for (int b = 0; b < 8; ++b)
#pragma unroll
            for (int j = 0; j < NV; ++j) acc[j] = fmaf(bf2f(w[b][j]), nr[b], acc[j]);
    }
    for (; e < e1; ++e) {
        int s = esrc[e];
        float nrm = dinv[s] * dn;
        vec_t w = hp[(size_t)s * 64 + lane];
#pragma unroll
        for (int j = 0; j < NV; ++j) acc[j] = fmaf(bf2f(w[j]), nrm, acc[j]);
    }
    vec_t vh, vl;
#pragma unroll
    for (int j = 0; j < NV; ++j) {
        u16 hb = f2bf(acc[j]);
        vh[j] = hb;
        vl[j] = f2bf(acc[j] - bf2f(hb));
    }
    ((vec_t*)z_hi)[(size_t)n * 64 + lane] = vh;
    ((vec_t*)z_lo)[(size_t)n * 64 + lane] = vl;
}

// ---------------------------------------------------------------- split-bf16 MFMA GEMM
// C = (Ah+Al)[M,K] @ (Bh+Bl)[K,N] + bias;  B transposed [N][K].
// BM=128, BN=128, BK=32; 8 waves (wave tile 64x32); double-buffered LDS (2 x 32KB).
// Counted-vmcnt pipeline (T4): STAGE(next); vmcnt(4); barrier; compute(cur); barrier.
// LDS swizzle: byte col ^= ((row>>1)&3)<<4  (64B rows: spreads 16 lanes over all 32 banks,
// 2-way = free; the previous (row&3) variant aliased with the row*16 bank term -> 4-way).
// 1-D grid with bijective XCD-chunked swizzle (m204) so same-A blocks share an XCD L2.
template <int K, bool RELU, bool OUT_BF16>
__global__ __launch_bounds__(512, 4) void gemm_mfma_kernel(
        const u16* __restrict__ Ah, const u16* __restrict__ Al, const u16* __restrict__ Bh,
        const u16* __restrict__ Bl, const float* __restrict__ bias, void* __restrict__ Cout,
        int M, int N) {
    // planes per buffer: 0=Ah 1=Al 2=Bh 3=Bl, each [128 rows][32 k] = 8 KB, rows 64 B
    __shared__ u16 lds[2][4][128 * 32];
    const int tid = threadIdx.x;
    const int lane = tid & 63;
    const int wid = tid >> 6;

    // bijective XCD-chunked swizzle
    const int nmt = (M + 127) / 128;
    const int total = nmt * 4;
    int bid = blockIdx.x;
    int q = total >> 3, r = total & 7;
    int xcd = bid & 7, p = bid >> 3;
    int lin = (xcd < r) ? (xcd * (q + 1) + p) : (r * (q + 1) + (xcd - r) * q + p);
    const int bm = (lin >> 2) * 128;
    const int bn = (lin & 3) * 128;

    const int wm = (wid & 1) * 64;   // 2 wave-rows
    const int wn = (wid >> 1) * 32;  // 4 wave-cols

    f32x4 acc[4][2];
#pragma unroll
    for (int i = 0; i < 4; ++i)
#pragma unroll
        for (int j = 0; j < 2; ++j) acc[i][j] = (f32x4){0.f, 0.f, 0.f, 0.f};

    // staging geometry: 512 chunks of 16B per plane; chunk = tid
    const int srow = tid >> 2;                    // 0..127
    const int scb = ((tid & 3) << 4);             // 0,16,32,48
    const int sscb = scb ^ (((srow >> 1) & 3) << 4);  // pre-swizzled source byte col
    const int grA = min(bm + srow, M - 1);
    const int grB = bn + srow;
    const char* srcAh = (const char*)(Ah + (size_t)grA * K) + sscb;
    const char* srcAl = (const char*)(Al + (size_t)grA * K) + sscb;
    const char* srcBh = (const char*)(Bh + (size_t)grB * K) + sscb;
    const char* srcBl = (const char*)(Bl + (size_t)grB * K) + sscb;
    const int dstoff = (wid * 64) << 4;  // wave-uniform LDS byte offset within plane

#define STAGE(buf, k0)                                                                   \
    do {                                                                                 \
        size_t kb2 = (size_t)(k0) * 2;                                                   \
        __builtin_amdgcn_global_load_lds(                                                \
            (const __attribute__((address_space(1))) void*)(srcAh + kb2),                \
            (__attribute__((address_space(3))) void*)((char*)&lds[buf][0][0] + dstoff),  \
            16, 0, 0);                                                                   \
        __builtin_amdgcn_global_load_lds(                                                \
            (const __attribute__((address_space(1))) void*)(srcAl + kb2),                \
            (__attribute__((address_space(3))) void*)((char*)&lds[buf][1][0] + dstoff),  \
            16, 0, 0);                                                                   \
        __builtin_amdgcn_global_load_lds(                                                \
            (const __attribute__((address_space(1))) void*)(srcBh + kb2),                \
            (__attribute__((address_space(3))) void*)((char*)&lds[buf][2][0] + dstoff),  \
            16, 0, 0);                                                                   \
        __builtin_amdgcn_global_load_lds(                                                \
            (const __attribute__((address_space(1))) void*)(srcBl + kb2),                \
            (__attribute__((address_space(3))) void*)((char*)&lds[buf][3][0] + dstoff),  \
            16, 0, 0);                                                                   \
    } while (0)

    STAGE(0, 0);

    const int NT = K / 32;
    const int kb = (lane >> 4) << 4;  // fragment k byte-offset within 64B row
#pragma unroll
    for (int t = 0; t < NT; ++t) {
        int cur = t & 1;
        if (t + 1 < NT) {
            STAGE(cur ^ 1, (t + 1) * 32);
            // wait only for the PREVIOUS tile's 4 staging loads; this iter's 4 stay in flight
            asm volatile("s_waitcnt vmcnt(4)" ::: "memory");
        } else {
            asm volatile("s_waitcnt vmcnt(0)" ::: "memory");
        }
        __builtin_amdgcn_s_barrier();          // all waves: buf[cur] fully populated
        asm volatile("" ::: "memory");         // fence: no ds_read hoisting above barrier

        const char* L = (const char*)&lds[cur][0][0];
        bf16x8 a_h[4], a_l[4], b_h[2], b_l[2];
#pragma unroll
        for (int i = 0; i < 4; ++i) {
            int ra = wm + i * 16 + (lane & 15);
            int off = ra * 64 + (kb ^ (((ra >> 1) & 3) << 4));
            a_h[i] = *(const bf16x8*)(L + off);
            a_l[i] = *(const bf16x8*)(L + 8192 + off);
        }
#pragma unroll
        for (int j = 0; j < 2; ++j) {
            int rb = wn + j * 16 + (lane & 15);
            int off = rb * 64 + (kb ^ (((rb >> 1) & 3) << 4));
            b_h[j] = *(const bf16x8*)(L + 16384 + off);
            b_l[j] = *(const bf16x8*)(L + 24576 + off);
        }
#pragma unroll
        for (int i = 0; i < 4; ++i)
#pragma unroll
            for (int j = 0; j < 2; ++j) {
                acc[i][j] = __builtin_amdgcn_mfma_f32_16x16x32_bf16(a_h[i], b_h[j], acc[i][j], 0, 0, 0);
                acc[i][j] = __builtin_amdgcn_mfma_f32_16x16x32_bf16(a_l[i], b_h[j], acc[i][j], 0, 0, 0);
                acc[i][j] = __builtin_amdgcn_mfma_f32_16x16x32_bf16(a_h[i], b_l[j], acc[i][j], 0, 0, 0);
            }
        asm volatile("" ::: "memory");
        __builtin_amdgcn_s_barrier();          // all waves done reading buf[cur]
    }
#undef STAGE

    // epilogue: C/D layout col=lane&15, row=(lane>>4)*4+t  (m89/m91 verified)
#pragma unroll
    for (int j = 0; j < 2; ++j) {
        int gc = bn + wn + j * 16 + (lane & 15);
        float bv = bias[gc];
#pragma unroll
        for (int i = 0; i < 4; ++i) {
#pragma unroll
            for (int t = 0; t < 4; ++t) {
                int gr = bm + wm + i * 16 + ((lane >> 4) << 2) + t;
                if (gr < M) {
                    float v = acc[i][j][t] + bv;
                    if (RELU) v = fmaxf(v, 0.f);
                    if (OUT_BF16)
                        ((u16*)Cout)[(size_t)gr * N + gc] = f2bf(v);
                    else
                        ((float*)Cout)[(size_t)gr * N + gc] = v;
                }
            }
        }
    }
}

// ---------------------------------------------------------------- launch
extern "C" void kernel_launch(void* const* d_in, const int* in_sizes, int n_in,
                              void* d_out, int out_size, void* d_ws, size_t ws_size,
                              hipStream_t stream) {
    const float* x  = (const float*)d_in[0];
    const int*   ei = (const int*)d_in[1];
    const float* W1 = (const float*)d_in[2];
    const float* b1 = (const float*)d_in[3];
    const float* W2 = (const float*)d_in[4];
    const float* b2 = (const float*)d_in[5];
    const int* src = ei;
    const int* dst = ei + N_EDGES;

    char* ws = (char*)d_ws;
    size_t off = 0;
    auto alloc = [&](size_t bytes) {
        void* p = ws + off;
        off = (off + bytes + 255) & ~(size_t)255;
        return p;
    };
    int*   deg     = (int*)alloc(N_NODES * 4);
    int*   row_ptr = (int*)alloc((N_NODES + 1) * 4);
    float* dinv    = (float*)alloc(N_NODES * 4);
    int*   esrc    = (int*)alloc(N_EDGES * 4);
    u16*   wt1_hi  = (u16*)alloc((size_t)IN_CH * HID_CH * 2);
    u16*   wt1_lo  = (u16*)alloc((size_t)IN_CH * HID_CH * 2);
    u16*   wt2_hi  = (u16*)alloc((size_t)HID_CH * HID_CH * 2);
    u16*   wt2_lo  = (u16*)alloc((size_t)HID_CH * HID_CH * 2);
    // overlay region: {xb, z1_hi, z1_lo} then {z2_hi, z2_lo}
    char*  R       = (char*)alloc((size_t)N_NODES * HID_CH * 2 * 2);  // 40.96 MB
    u16* xb    = (u16*)R;                                       // [N, 256]
    u16* z1_hi = (u16*)(R + (size_t)N_NODES * IN_CH * 2);       // [N, 256]
    u16* z1_lo = (u16*)(R + (size_t)N_NODES * IN_CH * 4);       // [N, 256]
    u16* z2_hi = (u16*)R;                                       // [N, 512] (over dead xb+z1_hi)
    u16* z2_lo = (u16*)(R + (size_t)N_NODES * HID_CH * 2);      // [N, 512] (over dead z1_lo)
    u16* h1    = (u16*)d_out;  // bf16 h1 scratch in d_out (dead before final GEMM writes)

    // CSR + dinv
    hipMemsetAsync(deg, 0, N_NODES * 4, stream);
    count_deg_kernel<<<(N_EDGES + 255) / 256, 256, 0, stream>>>(dst, deg, N_EDGES);
    dinv_kernel<<<(N_NODES + 255) / 256, 256, 0, stream>>>(deg, dinv, N_NODES);
    scan_kernel<<<1, 256, 0, stream>>>(deg, row_ptr, N_NODES);
    hipMemsetAsync(deg, 0, N_NODES * 4, stream);
    scatter_edges_kernel<<<(N_EDGES + 255) / 256, 256, 0, stream>>>(src, dst, row_ptr, deg, esrc,
                                                                    N_EDGES);

    // conversions
    f32_to_bf16_kernel<<<(N_NODES * IN_CH / 4 + 255) / 256, 256, 0, stream>>>(
        x, xb, N_NODES * IN_CH / 4);
    {
        dim3 g1(IN_CH / 64, HID_CH / 64);
        convert_w_kernel<IN_CH><<<g1, 256, 0, stream>>>(W1, wt1_hi, wt1_lo, HID_CH);
        dim3 g2(HID_CH / 64, HID_CH / 64);
        convert_w_kernel<HID_CH><<<g2, 256, 0, stream>>>(W2, wt2_hi, wt2_lo, HID_CH);
    }

    const int NMT = (N_NODES + 127) / 128;  // 157
    // layer 1: z1 = P @ xb ; h1 = relu(z1 @ W1 + b1)  (bf16 out)
    gather_agg_kernel<IN_CH><<<(N_NODES + 3) / 4, 256, 0, stream>>>(xb, esrc, row_ptr, dinv, z1_hi,
                                                                    z1_lo, N_NODES);
    gemm_mfma_kernel<IN_CH, true, true><<<NMT * 4, 512, 0, stream>>>(
        z1_hi, z1_lo, wt1_hi, wt1_lo, b1, h1, N_NODES, HID_CH);

    // layer 2: z2 = P @ h1 ; out = z2 @ W2 + b2  (fp32 out)
    gather_agg_kernel<HID_CH><<<(N_NODES + 3) / 4, 256, 0, stream>>>(h1, esrc, row_ptr, dinv,
                                                                     z2_hi, z2_lo, N_NODES);
    gemm_mfma_kernel<HID_CH, false, false><<<NMT * 4, 512, 0, stream>>>(
        z2_hi, z2_lo, wt2_hi, wt2_lo, b2, (float*)d_out, N_NODES, HID_CH);
}